// Round 3
// baseline (1413.426 us; speedup 1.0000x reference)
//
#include <hip/hip_runtime.h>
#include <hip/hip_cooperative_groups.h>
#include <hip/hip_bf16.h>
#include <stdint.h>
#include <math.h>

// TreeLSTM on MI355X — v11: persistent cooperative kernel for all 9 levels.
// v8/v9/v10 post-mortem: lev=9 pinned at 109-114 us across occupancy 2x,
// A-prefetch depth, epilogue vectorization -> per-level kernel has a
// structural floor, and ~150 us of the 431 total is per-level fixed cost
// (B re-staging every level, launch/drain gaps, latency-bound small levels).
// v11: ONE cooperative kernel, grid=256 blocks (1/CU) x 1024 thr; each block
// owns a fixed ct -> B-slice staged to LDS ONCE for the whole tree; levels
// separated by grid.sync(); XCD-affinity kept (rg&7 == pid&7). K-loop B
// (LDS) prefetch deepened to 2 steps ahead (bb[3][5]) — the untested lgkmcnt
// latency axis (~124 unified regs, still 4 waves/SIMD under (1024,4)).

namespace cg = cooperative_groups;

typedef __bf16 bf16x8 __attribute__((ext_vector_type(8)));
typedef float  f32x4  __attribute__((ext_vector_type(4)));
typedef int    i32x4  __attribute__((ext_vector_type(4)));

__device__ __forceinline__ float sigf(float x) { return 1.f / (1.f + __expf(-x)); }
__device__ __forceinline__ float tanhfast(float x) {
    return 1.f - 2.f / (__expf(2.f * x) + 1.f);   // stable at |x| large
}

// xg4[(v*256+k)*4 + g] = bW[g][k] + sum_i emb[v][i] * W[g][i][k]
__global__ void xg_prep(const float* __restrict__ emb, const float* __restrict__ W,
                        const float* __restrict__ bW, float* __restrict__ xg4) {
    int g = blockIdx.x >> 6, v = blockIdx.x & 63, k = threadIdx.x;
    __shared__ float e[256];
    e[k] = emb[v * 256 + k];
    __syncthreads();
    float s = bW[g * 256 + k];
    const float* Wg = W + g * 65536 + k;
#pragma unroll 4
    for (int i = 0; i < 256; i++) s += e[i] * Wg[i * 256];
    xg4[(v * 256 + k) * 4 + g] = s;
}

// Pack U into MFMA-fragment order: BtP[g][ct][ks][lane][e], e<8
// value = Ucat[g][col=ct*16+(lane&15)][k=ks*32+(lane>>4)*8+e]
// Ucat[g][col][k] = U[g][k<256?0:1][k&255][col]
__global__ void bt_prep(const float* __restrict__ U, __bf16* __restrict__ BtP) {
    int t = blockIdx.x * 256 + threadIdx.x;     // < 81920
    int g    = t >> 14;
    int r    = t & 16383;
    int ct   = r >> 10;
    int ks   = (r >> 6) & 15;
    int lane = t & 63;
    int lr = lane & 15, q = lane >> 4;
    int col = ct * 16 + lr;
    int kbase = ks * 32 + q * 8;
    bf16x8 v8;
#pragma unroll
    for (int e = 0; e < 8; e++) {
        int k = kbase + e;
        int s = k >> 8, kk = k & 255;
        v8[e] = (__bf16)U[((g * 2 + s) * 256 + kk) * 256 + col];
    }
    *(bf16x8*)(BtP + (long)t * 8) = v8;
}

__global__ void leaf_kernel(const int* __restrict__ ids, const float* __restrict__ xg4,
                            __bf16* __restrict__ h, __bf16* __restrict__ c) {
    int col = threadIdx.x;                 // 0..255
    int r0 = blockIdx.x * 32;              // 2048 blocks x 32 rows
    for (int r = r0; r < r0 + 32; r++) {
        int b = r >> 10, j = r & 1023;
        int id = ids[b * 2046 + 1022 + j];
        f32x4 xv = *(const f32x4*)(xg4 + (id * 256 + col) * 4);
        float ig = sigf(xv.y);
        float og = sigf(xv.z);
        float ug = tanhfast(xv.w);
        float cv = ig * ug;
        float hv = og * tanhfast(cv);
        h[r * 256 + col] = (__bf16)hv;
        c[r * 256 + col] = (__bf16)cv;
    }
}

// Persistent: 256 blocks (1/CU) x 1024 thr = 16 waves x 32 rows.
// Block pid: xcd = pid&7, ct = (pid>>3)&15, slot = pid>>7 (0..1).
// Level lev: row-groups rg = xcd + 8*slot + 16*k  (rg&7==xcd -> XCD-affine).
// B-slice (80 KB, ct-dependent, level-INdependent) staged to LDS once.
__global__ __launch_bounds__(1024, 4) void tree_levels(
    __bf16* __restrict__ h0, __bf16* __restrict__ c0,
    __bf16* __restrict__ h1, __bf16* __restrict__ c1,
    const __bf16* __restrict__ BtP, const float* __restrict__ xg4,
    const int* __restrict__ ids, float* __restrict__ rh_base) {
    __shared__ __bf16 Blds[5 * 16 * 512];     // 80 KB
    cg::grid_group grid = cg::this_grid();

    const int pid  = blockIdx.x;
    const int xcd  = pid & 7;
    const int ct   = (pid >> 3) & 15;
    const int slot = pid >> 7;                // 0..1
    const int tid  = threadIdx.x;
    const int wave = tid >> 6;
    const int lane = tid & 63;
    const int lr = lane & 15, q = lane >> 4;
    const int gcol = ct * 16 + lr;

    // ---- Stage B-slice -> LDS ONCE (fragment order, 16B/lane). ----
#pragma unroll
    for (int i = 0; i < 5; i++) {
        int cc = tid + i * 1024;
        int g = cc >> 10;
        int r = cc & 1023;
        *(i32x4*)(&Blds[g * 8192 + r * 8]) =
            *(const i32x4*)(BtP + (long)(g * 16 + ct) * 8192 + r * 8);
    }
    __syncthreads();

    for (int lev = 9; lev >= 1; lev--) {
        const int M  = 64 << lev;
        const int RG = (M + 511) >> 9;
        const int p  = (9 - lev) & 1;
        const __bf16* A  = p ? h1 : h0;
        const __bf16* Cp = p ? c1 : c0;
        __bf16* Ho = p ? h0 : h1;
        __bf16* Co = p ? c0 : c1;
        float* rh = (lev == 1) ? rh_base : nullptr;
        const int n = 1 << lev;

        for (int rg = xcd + 8 * slot; rg < RG; rg += 16) {
            const long wrow = (long)rg * 512 + wave * 32;
            if (wrow < M) {
                // A prefetch: 2-deep (af[3], (s+2)%3 rotation).
                const __bf16* Ap = A + (wrow + lr) * 512 + q * 8;
                bf16x8 af[3][2];
#pragma unroll
                for (int mt = 0; mt < 2; mt++) {
                    af[0][mt] = *(const bf16x8*)(Ap + mt * 8192);
                    af[1][mt] = *(const bf16x8*)(Ap + mt * 8192 + 32);
                }

                // Preload ids + children's c (hidden under the K-loop).
                int idv[2][4];
                __bf16 clv[2][4], crv[2][4];
#pragma unroll
                for (int mt = 0; mt < 2; mt++)
#pragma unroll
                    for (int v = 0; v < 4; v++) {
                        long grow = wrow + mt * 16 + q * 4 + v;
                        int b = (int)(grow >> lev);
                        int j = (int)(grow & (n - 1));
                        idv[mt][v] = ids[b * 2046 + (n - 2) + j];
                        clv[mt][v] = Cp[grow * 512 + gcol];
                        crv[mt][v] = Cp[grow * 512 + 256 + gcol];
                    }

                f32x4 acc[5][2];
#pragma unroll
                for (int g2 = 0; g2 < 5; g2++)
#pragma unroll
                    for (int mt = 0; mt < 2; mt++)
                        acc[g2][mt] = (f32x4){0.f, 0.f, 0.f, 0.f};

                // B from LDS: 2-deep prefetch (bb[3][5], (s+2)%3 rotation).
                bf16x8 bb[3][5];
#pragma unroll
                for (int g2 = 0; g2 < 5; g2++) {
                    bb[0][g2] = *(const bf16x8*)(&Blds[g2 * 8192 + lane * 8]);
                    bb[1][g2] = *(const bf16x8*)(&Blds[g2 * 8192 + 512 + lane * 8]);
                }

#pragma unroll
                for (int s = 0; s < 16; s++) {
                    if (s + 2 < 16) {
#pragma unroll
                        for (int g2 = 0; g2 < 5; g2++)
                            bb[(s + 2) % 3][g2] = *(const bf16x8*)(
                                &Blds[g2 * 8192 + (s + 2) * 512 + lane * 8]);
#pragma unroll
                        for (int mt = 0; mt < 2; mt++)
                            af[(s + 2) % 3][mt] =
                                *(const bf16x8*)(Ap + mt * 8192 + (s + 2) * 32);
                    }
#pragma unroll
                    for (int g2 = 0; g2 < 5; g2++)
#pragma unroll
                        for (int mt = 0; mt < 2; mt++)
                            acc[g2][mt] = __builtin_amdgcn_mfma_f32_16x16x32_bf16(
                                af[s % 3][mt], bb[s % 3][g2], acc[g2][mt], 0, 0, 0);
                }

                // Epilogue: gate combine. col=lane&15, row=q*4+v.
#pragma unroll
                for (int mt = 0; mt < 2; mt++) {
#pragma unroll
                    for (int v = 0; v < 4; v++) {
                        long grow = wrow + mt * 16 + q * 4 + v;
                        f32x4 xv = *(const f32x4*)(xg4 + (idv[mt][v] * 256 + gcol) * 4);
                        float fl = sigf(acc[0][mt][v] + xv.x);   // f_l,f_r share gate0
                        float fr = sigf(acc[1][mt][v] + xv.x);
                        float ig = sigf(acc[2][mt][v] + xv.y);
                        float og = sigf(acc[3][mt][v] + xv.z);
                        float ug = tanhfast(acc[4][mt][v] + xv.w);
                        float cv = ig * ug + fl * (float)clv[mt][v]
                                           + fr * (float)crv[mt][v];
                        float hv = og * tanhfast(cv);
                        Ho[grow * 256 + gcol] = (__bf16)hv;
                        Co[grow * 256 + gcol] = (__bf16)cv;
                        if (rh) rh[grow * 256 + gcol] = hv;
                    }
                }
            }
        }
        __threadfence();
        grid.sync();
    }
}

__global__ void scores_kernel(const float* __restrict__ rh, const float* __restrict__ Ws,
                              const float* __restrict__ bs, float* __restrict__ out) {
    int b = blockIdx.x;
    int t = threadIdx.x >> 6, lane = threadIdx.x & 63;
    float s = 0.f;
    for (int i = lane; i < 512; i += 64) s += rh[b * 512 + i] * Ws[i * 3 + t];
    for (int o = 32; o > 0; o >>= 1) s += __shfl_down(s, o);
    if (lane == 0) out[b * 3 + t] = s + bs[t];
}

extern "C" void kernel_launch(void* const* d_in, const int* in_sizes, int n_in,
                              void* d_out, int out_size, void* d_ws, size_t ws_size,
                              hipStream_t stream) {
    const int*   ids = (const int*)  d_in[0];
    const float* emb = (const float*)d_in[1];
    const float* W   = (const float*)d_in[2];
    const float* bW  = (const float*)d_in[3];
    const float* U   = (const float*)d_in[4];
    const float* Ws  = (const float*)d_in[5];
    const float* bs  = (const float*)d_in[6];
    float* out = (float*)d_out;   // [0:192) scores, [192:) root_hidden (64x512)

    char* ws = (char*)d_ws;
    float*  xg4 = (float*)ws;                   //   262144 B : xg4[64][256][4]
    __bf16* BtP = (__bf16*)(ws + 262144);       //  1310720 B : packed B fragments
    __bf16* h0  = (__bf16*)(ws + 1572864);      // 33554432 B : h ping (leaf-sized)
    __bf16* c0  = (__bf16*)(ws + 35127296);     // 33554432 B
    __bf16* h1  = (__bf16*)(ws + 68681728);     // 16777216 B : h pong
    __bf16* c1  = (__bf16*)(ws + 85458944);     // 16777216 B   (total 102236160 B)

    xg_prep<<<dim3(256), dim3(256), 0, stream>>>(emb, W, bW, xg4);
    bt_prep<<<dim3(320), dim3(256), 0, stream>>>(U, BtP);
    leaf_kernel<<<dim3(2048), dim3(256), 0, stream>>>(ids, xg4, h0, c0);

    float* rh_base = out + 192;
    void* args[] = {(void*)&h0, (void*)&c0, (void*)&h1, (void*)&c1,
                    (void*)&BtP, (void*)&xg4, (void*)&ids, (void*)&rh_base};
    hipLaunchCooperativeKernel(tree_levels, dim3(256), dim3(1024), args, 0, stream);

    scores_kernel<<<dim3(64), dim3(192), 0, stream>>>(out + 192, Ws, bs, out);
}

// Round 5
// 415.680 us; speedup vs baseline: 3.4003x; 3.4003x over previous
//
#include <hip/hip_runtime.h>
#include <hip/hip_bf16.h>
#include <stdint.h>
#include <math.h>

// TreeLSTM on MI355X — v12b: identical logic to v12 (round-3 submission hit an
// infra container failure, not a kernel error). Per-level launches with
// level-persistent BLOCKS: grid = 16 ct x NB (NB=min(RG,16)); each block
// stages its 80KB B-slice ONCE and loops over row-groups rg += NB
// (XCD-affine: gid%8 == rg%8 when NB==16). The 4-slot af rotation wraps the
// A-prefetch across the rg boundary (steps 14/15 fetch next-rg steps 0/1),
// so epilogue(k) overlaps K-loop(k+1); no barriers after the single stage.
// Body is v10's measured kernel otherwise.

typedef __bf16 bf16x8 __attribute__((ext_vector_type(8)));
typedef float  f32x4  __attribute__((ext_vector_type(4)));
typedef int    i32x4  __attribute__((ext_vector_type(4)));

__device__ __forceinline__ float sigf(float x) { return 1.f / (1.f + __expf(-x)); }
__device__ __forceinline__ float tanhfast(float x) {
    return 1.f - 2.f / (__expf(2.f * x) + 1.f);   // stable at |x| large
}

// xg4[(v*256+k)*4 + g] = bW[g][k] + sum_i emb[v][i] * W[g][i][k]
__global__ void xg_prep(const float* __restrict__ emb, const float* __restrict__ W,
                        const float* __restrict__ bW, float* __restrict__ xg4) {
    int g = blockIdx.x >> 6, v = blockIdx.x & 63, k = threadIdx.x;
    __shared__ float e[256];
    e[k] = emb[v * 256 + k];
    __syncthreads();
    float s = bW[g * 256 + k];
    const float* Wg = W + g * 65536 + k;
#pragma unroll 4
    for (int i = 0; i < 256; i++) s += e[i] * Wg[i * 256];
    xg4[(v * 256 + k) * 4 + g] = s;
}

// Pack U into MFMA-fragment order: BtP[g][ct][ks][lane][e], e<8
// value = Ucat[g][col=ct*16+(lane&15)][k=ks*32+(lane>>4)*8+e]
// Ucat[g][col][k] = U[g][k<256?0:1][k&255][col]
__global__ void bt_prep(const float* __restrict__ U, __bf16* __restrict__ BtP) {
    int t = blockIdx.x * 256 + threadIdx.x;     // < 81920
    int g    = t >> 14;
    int r    = t & 16383;
    int ct   = r >> 10;
    int ks   = (r >> 6) & 15;
    int lane = t & 63;
    int lr = lane & 15, q = lane >> 4;
    int col = ct * 16 + lr;
    int kbase = ks * 32 + q * 8;
    bf16x8 v8;
#pragma unroll
    for (int e = 0; e < 8; e++) {
        int k = kbase + e;
        int s = k >> 8, kk = k & 255;
        v8[e] = (__bf16)U[((g * 2 + s) * 256 + kk) * 256 + col];
    }
    *(bf16x8*)(BtP + (long)t * 8) = v8;
}

__global__ void leaf_kernel(const int* __restrict__ ids, const float* __restrict__ xg4,
                            __bf16* __restrict__ h, __bf16* __restrict__ c) {
    int col = threadIdx.x;                 // 0..255
    int r0 = blockIdx.x * 32;              // 2048 blocks x 32 rows
    for (int r = r0; r < r0 + 32; r++) {
        int b = r >> 10, j = r & 1023;
        int id = ids[b * 2046 + 1022 + j];
        f32x4 xv = *(const f32x4*)(xg4 + (id * 256 + col) * 4);
        float ig = sigf(xv.y);
        float og = sigf(xv.z);
        float ug = tanhfast(xv.w);
        float cv = ig * ug;
        float hv = og * tanhfast(cv);
        h[r * 256 + col] = (__bf16)hv;
        c[r * 256 + col] = (__bf16)cv;
    }
}

// Block = 1024 thr = 16 waves x 32 rows; one ct (16 cols), all 5 gates.
// Grid = 16*NB blocks. NB16=1 -> rgslot = gid&15, ct = gid>>4 (no runtime div).
__global__ __launch_bounds__(1024, 4) void level_kernel(
    const __bf16* __restrict__ A, const __bf16* __restrict__ Cprev,
    const __bf16* __restrict__ BtP, const float* __restrict__ xg4,
    const int* __restrict__ ids, __bf16* __restrict__ h_out,
    __bf16* __restrict__ c_out, float* __restrict__ rh_out,
    int lev, int M, int RG, int NB, int NB16) {
    __shared__ __bf16 Blds[5 * 16 * 512];     // 80 KB
    const int gid = blockIdx.x;
    int rgslot, ct;
    if (NB16) { rgslot = gid & 15; ct = gid >> 4; }   // XCD-affine: gid%8==rg%8
    else      { rgslot = gid % NB; ct = gid / NB; }
    const int tid  = threadIdx.x;
    const int wave = tid >> 6;
    const int lane = tid & 63;
    const int lr = lane & 15, q = lane >> 4;
    const int gcol = ct * 16 + lr;
    const int n = 1 << lev;

    // ---- Stage B-slice -> LDS ONCE per block (fragment order, 16B/lane). ----
#pragma unroll
    for (int i = 0; i < 5; i++) {
        int cc = tid + i * 1024;
        int g = cc >> 10;
        int r = cc & 1023;
        *(i32x4*)(&Blds[g * 8192 + r * 8]) =
            *(const i32x4*)(BtP + (long)(g * 16 + ct) * 8192 + r * 8);
    }
    __syncthreads();

    // ---- First rg: prologue A prefetch into slots 0,1. ----
    int rg0 = rgslot;
    long wrow = (long)rg0 * 512 + wave * 32;
    const __bf16* Ap = A + (wrow + lr) * 512 + q * 8;   // + mt*8192 + s*32
    bf16x8 af[4][2];
    if (wrow < M) {
#pragma unroll
        for (int mt = 0; mt < 2; mt++) {
            af[0][mt] = *(const bf16x8*)(Ap + mt * 8192);
            af[1][mt] = *(const bf16x8*)(Ap + mt * 8192 + 32);
        }
    }

    for (int rg = rg0; rg < RG; rg += NB) {
        wrow = (long)rg * 512 + wave * 32;
        const bool active = (wrow < M);

        // Next rg's A base (wrap to current on last rg -> harmless re-reads).
        int rgn = rg + NB;
        long wrown = (rgn < RG) ? ((long)rgn * 512 + wave * 32) : wrow;
        const __bf16* Apn = A + (wrown + lr) * 512 + q * 8;

        // ---- Preload ids + children's c (latency hides under the K-loop). --
        int idv[2][4];
        __bf16 clv[2][4], crv[2][4];
        if (active) {
#pragma unroll
            for (int mt = 0; mt < 2; mt++)
#pragma unroll
                for (int v = 0; v < 4; v++) {
                    long grow = wrow + mt * 16 + q * 4 + v;
                    int b = (int)(grow >> lev);
                    int j = (int)(grow & (n - 1));
                    idv[mt][v] = ids[b * 2046 + (n - 2) + j];
                    clv[mt][v] = Cprev[grow * 512 + gcol];
                    crv[mt][v] = Cprev[grow * 512 + 256 + gcol];
                }
        }

        if (active) {
            f32x4 acc[5][2];
#pragma unroll
            for (int g2 = 0; g2 < 5; g2++)
#pragma unroll
                for (int mt = 0; mt < 2; mt++)
                    acc[g2][mt] = (f32x4){0.f, 0.f, 0.f, 0.f};

            // B double-buffer from LDS (ds_read_b128, conflict-free).
            bf16x8 bb[2][5];
#pragma unroll
            for (int g2 = 0; g2 < 5; g2++)
                bb[0][g2] = *(const bf16x8*)(&Blds[g2 * 8192 + lane * 8]);

#pragma unroll
            for (int s = 0; s < 16; s++) {
                {   // A: 2 ahead; wraps into NEXT rg's steps 0,1 at s=14,15.
                    int sp = s + 2;
                    const __bf16* P = (sp < 16) ? Ap : Apn;
                    int so = sp & 15;
#pragma unroll
                    for (int mt = 0; mt < 2; mt++)
                        af[sp & 3][mt] = *(const bf16x8*)(P + mt * 8192 + so * 32);
                }
                if (s + 1 < 16) {                  // B: 1 step ahead from LDS
#pragma unroll
                    for (int g2 = 0; g2 < 5; g2++)
                        bb[(s + 1) & 1][g2] =
                            *(const bf16x8*)(&Blds[g2 * 8192 + (s + 1) * 512 + lane * 8]);
                }
#pragma unroll
                for (int g2 = 0; g2 < 5; g2++)
#pragma unroll
                    for (int mt = 0; mt < 2; mt++)
                        acc[g2][mt] = __builtin_amdgcn_mfma_f32_16x16x32_bf16(
                            af[s & 3][mt], bb[s & 1][g2], acc[g2][mt], 0, 0, 0);
            }

            // ---- Epilogue: gate combine. col=lane&15, row=q*4+v. ----
#pragma unroll
            for (int mt = 0; mt < 2; mt++) {
#pragma unroll
                for (int v = 0; v < 4; v++) {
                    long grow = wrow + mt * 16 + q * 4 + v;
                    f32x4 xv = *(const f32x4*)(xg4 + (idv[mt][v] * 256 + gcol) * 4);
                    float fl = sigf(acc[0][mt][v] + xv.x);   // f_l,f_r share gate0
                    float fr = sigf(acc[1][mt][v] + xv.x);
                    float ig = sigf(acc[2][mt][v] + xv.y);
                    float og = sigf(acc[3][mt][v] + xv.z);
                    float ug = tanhfast(acc[4][mt][v] + xv.w);
                    float cv = ig * ug + fl * (float)clv[mt][v]
                                       + fr * (float)crv[mt][v];
                    float hv = og * tanhfast(cv);
                    h_out[grow * 256 + gcol] = (__bf16)hv;
                    c_out[grow * 256 + gcol] = (__bf16)cv;
                    if (rh_out) rh_out[grow * 256 + gcol] = hv;
                }
            }
        }
        Ap = Apn;
    }
}

__global__ void scores_kernel(const float* __restrict__ rh, const float* __restrict__ Ws,
                              const float* __restrict__ bs, float* __restrict__ out) {
    int b = blockIdx.x;
    int t = threadIdx.x >> 6, lane = threadIdx.x & 63;
    float s = 0.f;
    for (int i = lane; i < 512; i += 64) s += rh[b * 512 + i] * Ws[i * 3 + t];
    for (int o = 32; o > 0; o >>= 1) s += __shfl_down(s, o);
    if (lane == 0) out[b * 3 + t] = s + bs[t];
}

extern "C" void kernel_launch(void* const* d_in, const int* in_sizes, int n_in,
                              void* d_out, int out_size, void* d_ws, size_t ws_size,
                              hipStream_t stream) {
    const int*   ids = (const int*)  d_in[0];
    const float* emb = (const float*)d_in[1];
    const float* W   = (const float*)d_in[2];
    const float* bW  = (const float*)d_in[3];
    const float* U   = (const float*)d_in[4];
    const float* Ws  = (const float*)d_in[5];
    const float* bs  = (const float*)d_in[6];
    float* out = (float*)d_out;   // [0:192) scores, [192:) root_hidden (64x512)

    char* ws = (char*)d_ws;
    float*  xg4 = (float*)ws;                   //   262144 B : xg4[64][256][4]
    __bf16* BtP = (__bf16*)(ws + 262144);       //  1310720 B : packed B fragments
    __bf16* h0  = (__bf16*)(ws + 1572864);      // 33554432 B : h ping (leaf-sized)
    __bf16* c0  = (__bf16*)(ws + 35127296);     // 33554432 B
    __bf16* h1  = (__bf16*)(ws + 68681728);     // 16777216 B : h pong
    __bf16* c1  = (__bf16*)(ws + 85458944);     // 16777216 B   (total 102236160 B)

    xg_prep<<<dim3(256), dim3(256), 0, stream>>>(emb, W, bW, xg4);
    bt_prep<<<dim3(320), dim3(256), 0, stream>>>(U, BtP);
    leaf_kernel<<<dim3(2048), dim3(256), 0, stream>>>(ids, xg4, h0, c0);

    __bf16* hb[2] = {h0, h1};
    __bf16* cb[2] = {c0, c1};
    int cur = 0;
    for (int lev = 9; lev >= 1; lev--) {
        int M = 64 << lev;                      // B * 2^lev rows
        int RG = M >> 9; if (RG < 1) RG = 1;
        int NB = (RG < 16) ? RG : 16;
        float* rh = (lev == 1) ? (out + 192) : nullptr;
        level_kernel<<<dim3(16 * NB), dim3(1024), 0, stream>>>(
            hb[cur], cb[cur], BtP, xg4, ids, hb[1 - cur], cb[1 - cur], rh,
            lev, M, RG, NB, (NB == 16) ? 1 : 0);
        cur = 1 - cur;
    }
    scores_kernel<<<dim3(64), dim3(192), 0, stream>>>(out + 192, Ws, bs, out);
}